// Round 1
// baseline (515.186 us; speedup 1.0000x reference)
//
#include <hip/hip_runtime.h>
#include <math.h>

#define WS   7
#define WS2  49
#define DISP 3
#define HEADS 8
#define HD   32
#define BATCH 16
#define IMGH 56
#define IMGW 56
#define NW   8      // windows per row/col

__global__ __launch_bounds__(256) void swca_kernel(
    const float* __restrict__ skip, const float* __restrict__ x,
    const float* __restrict__ Wq, const float* __restrict__ Wk,
    const float* __restrict__ Wv, const float* __restrict__ Wl,
    const float* __restrict__ pe, float* __restrict__ out)
{
    __shared__ float xh[WS2][HD + 1];   // x head-slice (later reused as attn@v output)
    __shared__ float sh[WS2][HD + 1];   // skip head-slice
    __shared__ float qT[WS2][HD + 1];
    __shared__ float kT[WS2][HD + 1];
    __shared__ float vT[WS2][HD + 1];
    __shared__ float s [WS2][WS2 + 1];  // 49x50 scores
    __shared__ float wq[HD * HD], wk[HD * HD], wv[HD * HD], wl[HD * HD]; // transposed: w[d*32+i] = W[i][d]
    __shared__ float pes[169];

    const int t    = threadIdx.x;
    const int blk  = blockIdx.x;
    const int head = blk & 7;
    const int win  = (blk >> 3) & 63;
    const int b    = blk >> 9;
    const int wy   = win >> 3, wx = win & 7;

    // ---- load weights (transposed) + pe ----
    for (int e = t; e < HD * HD; e += 256) {
        int i = e >> 5, d = e & 31;
        wq[d * HD + i] = Wq[e];
        wk[d * HD + i] = Wk[e];
        wv[d * HD + i] = Wv[e];
        wl[d * HD + i] = Wl[e];
    }
    if (t < 169) pes[t] = pe[t];

    // ---- gather x / skip head slices for this window (roll by +DISP) ----
    for (int e = t; e < WS2 * HD; e += 256) {
        int p = e >> 5, ch = e & 31;
        int py = p / WS, px = p % WS;
        int row = (wy * WS + py + DISP) % IMGH;
        int col = (wx * WS + px + DISP) % IMGW;
        int gi  = (b * IMGH * IMGW + row * IMGW + col) * (HEADS * HD) + head * HD + ch;
        xh[p][ch] = x[gi];
        sh[p][ch] = skip[gi];
    }
    __syncthreads();

    // ---- q, k, v projections ----
    for (int e = t; e < WS2 * HD; e += 256) {
        int p = e >> 5, i = e & 31;
        float aq = 0.f, ak = 0.f, av = 0.f;
        #pragma unroll
        for (int d = 0; d < HD; d++) {
            aq += xh[p][d] * wq[d * HD + i];
            ak += xh[p][d] * wk[d * HD + i];
            av += sh[p][d] * wv[d * HD + i];
        }
        qT[p][i] = aq; kT[p][i] = ak; vT[p][i] = av;
    }
    __syncthreads();

    // ---- scores = qk/sqrt(HD) + bias + mask ----
    const float scale = 0.17677669529663687f;  // 1/sqrt(32)
    const bool mrow = (wy == NW - 1);
    const bool mcol = (wx == NW - 1);
    for (int e = t; e < WS2 * WS2; e += 256) {
        int qi = e / WS2, ki = e % WS2;
        int qy = qi / WS, qx = qi % WS, ky = ki / WS, kx = ki % WS;
        bool masked = (mrow && ((qy >= 4) != (ky >= 4))) ||
                      (mcol && ((qx >= 4) != (kx >= 4)));
        float acc = 0.f;
        #pragma unroll
        for (int d = 0; d < HD; d++) acc += qT[qi][d] * kT[ki][d];
        float val = acc * scale + pes[(ky - qy + 6) * 13 + (kx - qx + 6)];
        s[qi][ki] = masked ? -INFINITY : val;
    }
    __syncthreads();

    // ---- softmax per row (thread t < 49 owns row t) ----
    if (t < WS2) {
        float m = -INFINITY;
        for (int k2 = 0; k2 < WS2; k2++) m = fmaxf(m, s[t][k2]);
        float sum = 0.f;
        for (int k2 = 0; k2 < WS2; k2++) { float ev = expf(s[t][k2] - m); s[t][k2] = ev; sum += ev; }
        float inv = 1.0f / sum;
        for (int k2 = 0; k2 < WS2; k2++) s[t][k2] *= inv;
    }
    __syncthreads();

    // ---- o = attn @ v (reuse xh as o) ----
    for (int e = t; e < WS2 * HD; e += 256) {
        int p = e >> 5, i = e & 31;
        float acc = 0.f;
        for (int k2 = 0; k2 < WS2; k2++) acc += s[p][k2] * vT[k2][i];
        xh[p][i] = acc;
    }
    __syncthreads();

    // ---- final projection + scatter (roll back) ----
    for (int e = t; e < WS2 * HD; e += 256) {
        int p = e >> 5, i = e & 31;
        float acc = 0.f;
        #pragma unroll
        for (int d = 0; d < HD; d++) acc += xh[p][d] * wl[d * HD + i];
        int py = p / WS, px = p % WS;
        int row = (wy * WS + py + DISP) % IMGH;
        int col = (wx * WS + px + DISP) % IMGW;
        int gi  = (b * IMGH * IMGW + row * IMGW + col) * (HEADS * HD) + head * HD + i;
        out[gi] = acc;
    }
}

extern "C" void kernel_launch(void* const* d_in, const int* in_sizes, int n_in,
                              void* d_out, int out_size, void* d_ws, size_t ws_size,
                              hipStream_t stream) {
    const float* skip = (const float*)d_in[0];
    const float* x    = (const float*)d_in[1];
    const float* Wq   = (const float*)d_in[2];
    const float* Wk   = (const float*)d_in[3];
    const float* Wv   = (const float*)d_in[4];
    const float* Wl   = (const float*)d_in[5];
    const float* pe   = (const float*)d_in[6];
    float* out = (float*)d_out;

    dim3 grid(BATCH * 64 * HEADS);   // (b, window, head)
    dim3 block(256);
    swca_kernel<<<grid, block, 0, stream>>>(skip, x, Wq, Wk, Wv, Wl, pe, out);
}

// Round 2
// 318.079 us; speedup vs baseline: 1.6197x; 1.6197x over previous
//
#include <hip/hip_runtime.h>
#include <math.h>

#define WS    7
#define WS2   49
#define DISP  3
#define HEADS 8
#define HD    32
#define BATCH 16
#define IMGH  56
#define IMGW  56
#define NW    8

// LDS float offsets (row stride 36 floats = 144B, 16B-aligned, +4 bank skew/row)
#define SD    36
#define SS    52            // score row stride (52 floats = 208B, 16B-aligned)
#define OFF_XH 0            // 49*36 = 1764
#define OFF_SH 1764
#define OFF_QT 3528
#define OFF_KT 5292
#define OFF_VT 7056
#define OFF_PE 8820         // 169 -> pad 176
#define SMEM_F 8996         // 35984 bytes
// overlays: s  -> OFF_XH (49*52 = 2548 <= 3528: xh+sh dead after proj)
//           o  -> OFF_QT (dead after scores)

__global__ __launch_bounds__(256, 4) void swca_kernel(
    const float* __restrict__ skip, const float* __restrict__ x,
    const float* __restrict__ Wq, const float* __restrict__ Wk,
    const float* __restrict__ Wv, const float* __restrict__ Wl,
    const float* __restrict__ pe, float* __restrict__ out)
{
    __shared__ float smem[SMEM_F];

    const int t    = threadIdx.x;
    const int blk  = blockIdx.x;
    const int head = blk & 7;
    const int win  = (blk >> 3) & 63;
    const int b    = blk >> 9;
    const int wy   = win >> 3, wx = win & 7;
    const int i    = t & 31;        // owned output column for proj phases
    const int pg   = t >> 5;        // row group (0..7)

    // ---- phase 0: gather x/skip head slices (vectorized) + pe ----
    if (t < 169) smem[OFF_PE + t] = pe[t];
    for (int e = t; e < WS2 * 8; e += 256) {
        int p = e >> 3, c4 = e & 7;
        int py = p / WS, px = p % WS;
        int row = (wy * WS + py + DISP) % IMGH;
        int col = (wx * WS + px + DISP) % IMGW;
        size_t gi = ((size_t)(b * IMGH * IMGW + row * IMGW + col)) * (HEADS * HD)
                  + head * HD + c4 * 4;
        float4 xv = *(const float4*)(x + gi);
        float4 sv = *(const float4*)(skip + gi);
        *(float4*)(smem + OFF_XH + p * SD + c4 * 4) = xv;
        *(float4*)(smem + OFF_SH + p * SD + c4 * 4) = sv;
    }
    __syncthreads();

    // ---- phase 1: projections. thread owns column i; weight row i in regs ----
    {   // q
        float wc[HD];
        #pragma unroll
        for (int d4 = 0; d4 < 8; ++d4) {
            float4 w4 = *(const float4*)(Wq + i * HD + d4 * 4);
            wc[4*d4] = w4.x; wc[4*d4+1] = w4.y; wc[4*d4+2] = w4.z; wc[4*d4+3] = w4.w;
        }
        for (int p = pg; p < WS2; p += 8) {
            float acc = 0.f;
            #pragma unroll
            for (int d4 = 0; d4 < 8; ++d4) {
                float4 xv = *(const float4*)(smem + OFF_XH + p * SD + d4 * 4);
                acc += xv.x * wc[4*d4] + xv.y * wc[4*d4+1] + xv.z * wc[4*d4+2] + xv.w * wc[4*d4+3];
            }
            smem[OFF_QT + p * SD + i] = acc;
        }
    }
    {   // k (stored with column-chunk XOR swizzle on (p>>2)&7)
        float wc[HD];
        #pragma unroll
        for (int d4 = 0; d4 < 8; ++d4) {
            float4 w4 = *(const float4*)(Wk + i * HD + d4 * 4);
            wc[4*d4] = w4.x; wc[4*d4+1] = w4.y; wc[4*d4+2] = w4.z; wc[4*d4+3] = w4.w;
        }
        for (int p = pg; p < WS2; p += 8) {
            float acc = 0.f;
            #pragma unroll
            for (int d4 = 0; d4 < 8; ++d4) {
                float4 xv = *(const float4*)(smem + OFF_XH + p * SD + d4 * 4);
                acc += xv.x * wc[4*d4] + xv.y * wc[4*d4+1] + xv.z * wc[4*d4+2] + xv.w * wc[4*d4+3];
            }
            int c = ((i >> 2) ^ ((p >> 2) & 7));
            smem[OFF_KT + p * SD + (c << 2) + (i & 3)] = acc;
        }
    }
    {   // v
        float wc[HD];
        #pragma unroll
        for (int d4 = 0; d4 < 8; ++d4) {
            float4 w4 = *(const float4*)(Wv + i * HD + d4 * 4);
            wc[4*d4] = w4.x; wc[4*d4+1] = w4.y; wc[4*d4+2] = w4.z; wc[4*d4+3] = w4.w;
        }
        for (int p = pg; p < WS2; p += 8) {
            float acc = 0.f;
            #pragma unroll
            for (int d4 = 0; d4 < 8; ++d4) {
                float4 sv = *(const float4*)(smem + OFF_SH + p * SD + d4 * 4);
                acc += sv.x * wc[4*d4] + sv.y * wc[4*d4+1] + sv.z * wc[4*d4+2] + sv.w * wc[4*d4+3];
            }
            smem[OFF_VT + p * SD + i] = acc;
        }
    }
    __syncthreads();

    // ---- phase 2: scores (overwrites xh/sh region with s) ----
    const float scale = 0.17677669529663687f;
    const bool mrow = (wy == NW - 1);
    const bool mcol = (wx == NW - 1);
    for (int e = t; e < WS2 * 13; e += 256) {
        int qi = e / 13, kq = e % 13;
        int qy = qi / WS, qx = qi % WS;
        float4 qv[8];
        #pragma unroll
        for (int d4 = 0; d4 < 8; ++d4)
            qv[d4] = *(const float4*)(smem + OFF_QT + qi * SD + d4 * 4);
        float res[4];
        #pragma unroll
        for (int j = 0; j < 4; ++j) {
            int ki = kq * 4 + j;
            if (ki < WS2) {
                float acc = 0.f;
                #pragma unroll
                for (int d4 = 0; d4 < 8; ++d4) {
                    int c = (d4 ^ (kq & 7));
                    float4 kv = *(const float4*)(smem + OFF_KT + ki * SD + (c << 2));
                    acc += qv[d4].x * kv.x + qv[d4].y * kv.y + qv[d4].z * kv.z + qv[d4].w * kv.w;
                }
                int ky = ki / WS, kx = ki % WS;
                bool masked = (mrow && ((qy >= 4) != (ky >= 4))) ||
                              (mcol && ((qx >= 4) != (kx >= 4)));
                res[j] = masked ? -INFINITY
                                : acc * scale + smem[OFF_PE + (ky - qy + 6) * 13 + (kx - qx + 6)];
            } else res[j] = -INFINITY;
        }
        float4 r4 = make_float4(res[0], res[1], res[2], res[3]);
        *(float4*)(smem + qi * SS + kq * 4) = r4;
    }
    __syncthreads();

    // ---- phase 3: softmax, 4 lanes per row ----
    if (t < WS2 * 4) {
        int r = t >> 2, q4 = t & 3;
        float* row = smem + r * SS;
        float m = -INFINITY;
        #pragma unroll
        for (int j = 0; j < 13; ++j) m = fmaxf(m, row[q4 * 13 + j]);
        m = fmaxf(m, __shfl_xor(m, 1));
        m = fmaxf(m, __shfl_xor(m, 2));
        float sum = 0.f;
        #pragma unroll
        for (int j = 0; j < 13; ++j) {
            float ev = __expf(row[q4 * 13 + j] - m);
            row[q4 * 13 + j] = ev;
            sum += ev;
        }
        sum += __shfl_xor(sum, 1);
        sum += __shfl_xor(sum, 2);
        float inv = 1.0f / sum;
        #pragma unroll
        for (int j = 0; j < 13; ++j) row[q4 * 13 + j] *= inv;
    }
    __syncthreads();

    // ---- phase 4: o = attn @ v  (o overlays qT) ----
    for (int e = t; e < WS2 * 8; e += 256) {
        int p = e >> 3, iq = e & 7;
        float4 acc = make_float4(0.f, 0.f, 0.f, 0.f);
        #pragma unroll
        for (int kk = 0; kk < 13; ++kk) {
            float4 s4 = *(const float4*)(smem + p * SS + kk * 4);
            #pragma unroll
            for (int j = 0; j < 4; ++j) {
                int k2 = kk * 4 + j;
                float sj = (j == 0) ? s4.x : (j == 1) ? s4.y : (j == 2) ? s4.z : s4.w;
                float4 vv = *(const float4*)(smem + OFF_VT + k2 * SD + iq * 4);
                acc.x += sj * vv.x; acc.y += sj * vv.y; acc.z += sj * vv.z; acc.w += sj * vv.w;
            }
        }
        *(float4*)(smem + OFF_QT + p * SD + iq * 4) = acc;
    }
    __syncthreads();

    // ---- phase 5: final projection + scatter ----
    {
        float wc[HD];
        #pragma unroll
        for (int d4 = 0; d4 < 8; ++d4) {
            float4 w4 = *(const float4*)(Wl + i * HD + d4 * 4);
            wc[4*d4] = w4.x; wc[4*d4+1] = w4.y; wc[4*d4+2] = w4.z; wc[4*d4+3] = w4.w;
        }
        for (int p = pg; p < WS2; p += 8) {
            float acc = 0.f;
            #pragma unroll
            for (int d4 = 0; d4 < 8; ++d4) {
                float4 ov = *(const float4*)(smem + OFF_QT + p * SD + d4 * 4);
                acc += ov.x * wc[4*d4] + ov.y * wc[4*d4+1] + ov.z * wc[4*d4+2] + ov.w * wc[4*d4+3];
            }
            int py = p / WS, px = p % WS;
            int row = (wy * WS + py + DISP) % IMGH;
            int col = (wx * WS + px + DISP) % IMGW;
            size_t gi = ((size_t)(b * IMGH * IMGW + row * IMGW + col)) * (HEADS * HD)
                      + head * HD + i;
            out[gi] = acc;
        }
    }
}

extern "C" void kernel_launch(void* const* d_in, const int* in_sizes, int n_in,
                              void* d_out, int out_size, void* d_ws, size_t ws_size,
                              hipStream_t stream) {
    const float* skip = (const float*)d_in[0];
    const float* x    = (const float*)d_in[1];
    const float* Wq   = (const float*)d_in[2];
    const float* Wk   = (const float*)d_in[3];
    const float* Wv   = (const float*)d_in[4];
    const float* Wl   = (const float*)d_in[5];
    const float* pe   = (const float*)d_in[6];
    float* out = (float*)d_out;

    dim3 grid(BATCH * 64 * HEADS);
    dim3 block(256);
    swca_kernel<<<grid, block, 0, stream>>>(skip, x, Wq, Wk, Wv, Wl, pe, out);
}

// Round 5
// 175.628 us; speedup vs baseline: 2.9334x; 1.8111x over previous
//
#include <hip/hip_runtime.h>
#include <math.h>

#define WS    7
#define WS2   49
#define DISP  3
#define HEADS 8
#define HD    32
#define IMGH  56
#define IMGW  56

typedef __attribute__((ext_vector_type(8))) __bf16 bf16x8;
typedef __attribute__((ext_vector_type(8))) short short8;
typedef __attribute__((ext_vector_type(4))) short short4v;
typedef __attribute__((ext_vector_type(4))) float f32x4;

__device__ __forceinline__ short f2bf(float f) {
  unsigned u = __builtin_bit_cast(unsigned, f);
  unsigned r = (u + 0x7fffu + ((u >> 16) & 1u)) >> 16;
  return (short)r;
}
__device__ __forceinline__ float bf2f(short s) {
  unsigned u = ((unsigned)(unsigned short)s) << 16;
  return __builtin_bit_cast(float, u);
}

// ---------------- prep kernel: fused weights + bias tables into d_ws ----------------
// ws layout (shorts): [0..1280) Wqkt[32][40]  (Wqkt[n][k] = scale*(Wq^T Wk)[k][n])
//                     [1280..2560) W2r[32][40] (W2r[m][n] = (Wl@Wv)[m][n])
//                     [2560..2560+13328) bias[4][49][68] bf16 (variant = mrow*2+mcol)
__global__ void prep_kernel(const float* __restrict__ Wq, const float* __restrict__ Wk,
                            const float* __restrict__ Wv, const float* __restrict__ Wl,
                            const float* __restrict__ pe, short* __restrict__ wsW,
                            short* __restrict__ wsB) {
  __shared__ float lw[4096];
  __shared__ float lpe[176];
  const int t = threadIdx.x;
  const int gid = blockIdx.x * 256 + t;   // 16 blocks x 256
  for (int i = t; i < 1024; i += 256) {
    lw[i] = Wq[i]; lw[1024 + i] = Wk[i]; lw[2048 + i] = Wv[i]; lw[3072 + i] = Wl[i];
  }
  if (t < 169) lpe[t] = pe[t];
  __syncthreads();
  if (gid < 1024) {              // Wqk entry (k,n): sum_d Wq[d][k]*Wk[d][n]
    int k = gid >> 5, n = gid & 31; float acc = 0.f;
    #pragma unroll
    for (int d = 0; d < 32; d++) acc += lw[d * 32 + k] * lw[1024 + d * 32 + n];
    wsW[n * 40 + k] = f2bf(acc * 0.17677669529663687f);
  } else if (gid < 2048) {       // W2 entry (m,n): sum_d Wl[m][d]*Wv[d][n]
    int e = gid - 1024; int m = e >> 5, n = e & 31; float acc = 0.f;
    #pragma unroll
    for (int d = 0; d < 32; d++) acc += lw[3072 + m * 32 + d] * lw[2048 + d * 32 + n];
    wsW[1280 + m * 40 + n] = f2bf(acc);
  }
  for (int e = gid; e < 13328; e += 4096) {
    int v = e / 3332, r2 = e % 3332, q = r2 / 68, k = r2 % 68;
    float val;
    if (k >= 49) val = -INFINITY;
    else {
      int qy = q / 7, qx = q % 7, ky = k / 7, kx = k % 7;
      bool masked = ((v & 2) && ((qy >= 4) != (ky >= 4))) ||
                    ((v & 1) && ((qx >= 4) != (kx >= 4)));
      val = masked ? -INFINITY : lpe[(ky - qy + 6) * 13 + (kx - qx + 6)];
    }
    wsB[e] = f2bf(val);
  }
}

// ---------------- main kernel: block=(b,win), 4 waves, 2 heads/wave ----------------
// LDS map (bytes): 0 biasb[49][68]s (6664, pad 6672) | 6672 wqkt[32][40]s | 9232 w2r[32][40]s
//                  | 11792 gaddr[64]i | 12048 arenas 4x13056
// arena: Tb[64][36]s (4608) overlaid by Pb[64][68]s (8704) at 0; UT[32][68]s (4352) at 8704
__global__ __launch_bounds__(256, 2) void swca_kernel(
    const float* __restrict__ skip, const float* __restrict__ x,
    const short* __restrict__ wsW, const short* __restrict__ wsB,
    float* __restrict__ out) {
  __shared__ __align__(16) char smem[64272];
  short* biasb = (short*)smem;
  short* wqkt  = (short*)(smem + 6672);
  short* w2r   = (short*)(smem + 9232);
  int*   gaddr = (int*)(smem + 11792);
  char*  arena = smem + 12048;

  const int t = threadIdx.x, blk = blockIdx.x;
  const int win = blk & 63, b = blk >> 6, wy = win >> 3, wx = win & 7;

  { // setup copies
    int v = ((wy == 7) ? 2 : 0) | ((wx == 7) ? 1 : 0);
    const int* bs = (const int*)(wsB + v * 3332);
    int* bd = (int*)biasb;
    for (int i = t; i < 1666; i += 256) bd[i] = bs[i];   // 49*68 shorts = 1666 ints (was 833: half-copied -> LDS garbage -> NaN)
    const int* wsrc = (const int*)wsW;   // 2560 shorts = 1280 ints, contiguous wqkt+w2r
    int* wdst = (int*)wqkt;
    for (int i = t; i < 1280; i += 256) wdst[i] = wsrc[i];
    if (t < 64) {
      int p = t, ga = 0;
      if (p < 49) {
        int py = p / 7, px = p % 7;
        int r = (wy * 7 + py + DISP) % IMGH, c = (wx * 7 + px + DISP) % IMGW;
        ga = (b * 3136 + r * 56 + c) * 256;
      }
      gaddr[t] = ga;
    }
  }
  __syncthreads();

  const int w = t >> 6, l = t & 63;
  const int lrow = l & 15, g = l >> 4, lk8 = g * 8;
  short* Tb = (short*)(arena + w * 13056);
  short* Pb = (short*)(arena + w * 13056);
  short* UT = (short*)(arena + w * 13056 + 8704);
  const f32x4 zero = {0.f, 0.f, 0.f, 0.f};

  for (int hh = 0; hh < 2; hh++) {
    const int h = w * 2 + hh;
    // ---- A-frags direct from global (f32 -> bf16) ----
    bf16x8 ax[4], asf[4];
    #pragma unroll
    for (int tm = 0; tm < 4; tm++) {
      short8 sa = {0,0,0,0,0,0,0,0}, ss = {0,0,0,0,0,0,0,0};
      int p = tm * 16 + lrow;
      if (p < 49) {
        int ga = gaddr[p] + h * 32 + lk8;
        float4 x0 = *(const float4*)(x + ga);
        float4 x1 = *(const float4*)(x + ga + 4);
        float4 s0 = *(const float4*)(skip + ga);
        float4 s1 = *(const float4*)(skip + ga + 4);
        sa[0]=f2bf(x0.x); sa[1]=f2bf(x0.y); sa[2]=f2bf(x0.z); sa[3]=f2bf(x0.w);
        sa[4]=f2bf(x1.x); sa[5]=f2bf(x1.y); sa[6]=f2bf(x1.z); sa[7]=f2bf(x1.w);
        ss[0]=f2bf(s0.x); ss[1]=f2bf(s0.y); ss[2]=f2bf(s0.z); ss[3]=f2bf(s0.w);
        ss[4]=f2bf(s1.x); ss[5]=f2bf(s1.y); ss[6]=f2bf(s1.z); ss[7]=f2bf(s1.w);
      }
      ax[tm]  = __builtin_bit_cast(bf16x8, sa);
      asf[tm] = __builtin_bit_cast(bf16x8, ss);
    }
    // ---- weight B-frags ----
    bf16x8 bq[2], bw[2];
    #pragma unroll
    for (int tn = 0; tn < 2; tn++) {
      int n = tn * 16 + lrow;
      bq[tn] = *(const bf16x8*)(wqkt + n * 40 + lk8);
      bw[tn] = *(const bf16x8*)(w2r  + n * 40 + lk8);
    }
    // ---- T = X@Wqk -> Tb ; U = S@W2^T -> UT ----
    #pragma unroll
    for (int tm = 0; tm < 4; tm++) {
      int row0 = tm * 16 + g * 4;
      #pragma unroll
      for (int tn = 0; tn < 2; tn++) {
        int col = tn * 16 + lrow;
        f32x4 tD = __builtin_amdgcn_mfma_f32_16x16x32_bf16(ax[tm], bq[tn], zero, 0, 0, 0);
        Tb[(row0 + 0) * 36 + col] = f2bf(tD[0]);
        Tb[(row0 + 1) * 36 + col] = f2bf(tD[1]);
        Tb[(row0 + 2) * 36 + col] = f2bf(tD[2]);
        Tb[(row0 + 3) * 36 + col] = f2bf(tD[3]);
        f32x4 uD = __builtin_amdgcn_mfma_f32_16x16x32_bf16(asf[tm], bw[tn], zero, 0, 0, 0);
        short4v u4 = { f2bf(uD[0]), f2bf(uD[1]), f2bf(uD[2]), f2bf(uD[3]) };
        *(short4v*)(UT + col * 68 + row0) = u4;
      }
    }
    // ---- S^T = X @ T^T (b-frags = rows of Tb) ----
    bf16x8 bT[4];
    #pragma unroll
    for (int tn = 0; tn < 4; tn++) {
      int n = tn * 16 + lrow;
      short4v lo = *(const short4v*)(Tb + n * 36 + lk8);
      short4v hi = *(const short4v*)(Tb + n * 36 + lk8 + 4);
      short8 c; c[0]=lo[0];c[1]=lo[1];c[2]=lo[2];c[3]=lo[3];
                c[4]=hi[0];c[5]=hi[1];c[6]=hi[2];c[7]=hi[3];
      bT[tn] = __builtin_bit_cast(bf16x8, c);
    }
    f32x4 st[4][4];
    #pragma unroll
    for (int ti = 0; ti < 4; ti++)
      #pragma unroll
      for (int tj = 0; tj < 4; tj++)
        st[ti][tj] = __builtin_amdgcn_mfma_f32_16x16x32_bf16(ax[ti], bT[tj], zero, 0, 0, 0);
    // ---- bias + softmax (q = tj*16+lrow fixed per lane; k across g,reg) ----
    #pragma unroll
    for (int tj = 0; tj < 4; tj++) {
      int q = tj * 16 + lrow;
      int qc = q > 48 ? 48 : q;
      float vv[4][4]; float mx = -INFINITY;
      #pragma unroll
      for (int ti = 0; ti < 4; ti++) {
        int k0 = ti * 16 + g * 4;
        short4v b4 = *(const short4v*)(biasb + qc * 68 + k0);
        vv[ti][0] = st[ti][tj][0] + bf2f(b4[0]);
        vv[ti][1] = st[ti][tj][1] + bf2f(b4[1]);
        vv[ti][2] = st[ti][tj][2] + bf2f(b4[2]);
        vv[ti][3] = st[ti][tj][3] + bf2f(b4[3]);
        mx = fmaxf(mx, fmaxf(fmaxf(vv[ti][0], vv[ti][1]), fmaxf(vv[ti][2], vv[ti][3])));
      }
      mx = fmaxf(mx, __shfl_xor(mx, 16));
      mx = fmaxf(mx, __shfl_xor(mx, 32));
      float sum = 0.f;
      #pragma unroll
      for (int ti = 0; ti < 4; ti++) {
        vv[ti][0] = __expf(vv[ti][0] - mx); sum += vv[ti][0];
        vv[ti][1] = __expf(vv[ti][1] - mx); sum += vv[ti][1];
        vv[ti][2] = __expf(vv[ti][2] - mx); sum += vv[ti][2];
        vv[ti][3] = __expf(vv[ti][3] - mx); sum += vv[ti][3];
      }
      sum += __shfl_xor(sum, 16);
      sum += __shfl_xor(sum, 32);
      float inv = 1.f / sum;
      #pragma unroll
      for (int ti = 0; ti < 4; ti++) {
        int k0 = ti * 16 + g * 4;
        short4v p4 = { f2bf(vv[ti][0] * inv), f2bf(vv[ti][1] * inv),
                       f2bf(vv[ti][2] * inv), f2bf(vv[ti][3] * inv) };
        *(short4v*)(Pb + q * 68 + k0) = p4;
      }
    }
    // ---- out = P @ U ----
    f32x4 oD[4][2];
    #pragma unroll
    for (int tr = 0; tr < 4; tr++)
      #pragma unroll
      for (int tn = 0; tn < 2; tn++) oD[tr][tn] = zero;
    #pragma unroll
    for (int ks = 0; ks < 2; ks++) {
      int kof = ks * 32 + lk8;
      bf16x8 aP[4], bU[2];
      #pragma unroll
      for (int tr = 0; tr < 4; tr++) {
        int q = tr * 16 + lrow;
        short4v lo = *(const short4v*)(Pb + q * 68 + kof);
        short4v hi = *(const short4v*)(Pb + q * 68 + kof + 4);
        short8 c; c[0]=lo[0];c[1]=lo[1];c[2]=lo[2];c[3]=lo[3];
                  c[4]=hi[0];c[5]=hi[1];c[6]=hi[2];c[7]=hi[3];
        aP[tr] = __builtin_bit_cast(bf16x8, c);
      }
      #pragma unroll
      for (int tn = 0; tn < 2; tn++) {
        int n = tn * 16 + lrow;
        short4v lo = *(const short4v*)(UT + n * 68 + kof);
        short4v hi = *(const short4v*)(UT + n * 68 + kof + 4);
        short8 c; c[0]=lo[0];c[1]=lo[1];c[2]=lo[2];c[3]=lo[3];
                  c[4]=hi[0];c[5]=hi[1];c[6]=hi[2];c[7]=hi[3];
        bU[tn] = __builtin_bit_cast(bf16x8, c);
      }
      #pragma unroll
      for (int tr = 0; tr < 4; tr++)
        #pragma unroll
        for (int tn = 0; tn < 2; tn++)
          oD[tr][tn] = __builtin_amdgcn_mfma_f32_16x16x32_bf16(aP[tr], bU[tn], oD[tr][tn], 0, 0, 0);
    }
    // ---- store (coalesced 16-lane channel runs) ----
    #pragma unroll
    for (int tr = 0; tr < 4; tr++) {
      int p0 = tr * 16 + g * 4;
      #pragma unroll
      for (int r = 0; r < 4; r++) {
        int p = p0 + r;
        if (p < 49) {
          int ga = gaddr[p] + h * 32;
          out[ga + lrow]      = oD[tr][0][r];
          out[ga + 16 + lrow] = oD[tr][1][r];
        }
      }
    }
  }
}

extern "C" void kernel_launch(void* const* d_in, const int* in_sizes, int n_in,
                              void* d_out, int out_size, void* d_ws, size_t ws_size,
                              hipStream_t stream) {
  const float* skip = (const float*)d_in[0];
  const float* x    = (const float*)d_in[1];
  const float* Wq   = (const float*)d_in[2];
  const float* Wk   = (const float*)d_in[3];
  const float* Wv   = (const float*)d_in[4];
  const float* Wl   = (const float*)d_in[5];
  const float* pe   = (const float*)d_in[6];
  float* out = (float*)d_out;
  short* wsW = (short*)d_ws;
  short* wsB = wsW + 2560;

  prep_kernel<<<16, 256, 0, stream>>>(Wq, Wk, Wv, Wl, pe, wsW, wsB);
  swca_kernel<<<16 * 64, 256, 0, stream>>>(skip, x, wsW, wsB, out);
}